// Round 1
// baseline (732.058 us; speedup 1.0000x reference)
//
#include <hip/hip_runtime.h>

// SNN direction decoder, fused: FC1 GEMM (fp32) + LIF scan + FC2 reduce.
// B=256, T=100, I=512, H=1024, C=8.
// Block = 256 threads, owns 8 batches x 128 h. T processed in 7 chunks of 16:
// per chunk a 128x128x512 GEMM tile (rows = 8b x 16t), then scan via LDS.

#define B_  256
#define T_  100
#define I_  512
#define H_  1024
#define C_  8
#define TC  16     // timesteps per chunk
#define BB  8      // batches per block
#define MT  128    // tile rows  (BB*TC)
#define NT  128    // tile cols  (h per block)
#define KB  16     // k-slice
#define NCHUNK 7   // ceil(100/16)

union SM {
    struct { float As[KB][MT]; float Bs[KB][NT]; } s;  // 16 KB during GEMM
    float Cs[64][132];                                  // 33.8 KB during scan (pad 132 vs 128)
};

__device__ __forceinline__ void lif_step(float& mem, float& ss, float cur) {
    // snntorch Leaky, reset_mechanism='subtract', THRESH=1, BETA=0.9
    float reset = (mem > 1.0f) ? 1.0f : 0.0f;
    mem = 0.9f * mem + cur - reset;
    ss += (mem > 1.0f) ? 1.0f : 0.0f;
}

__global__ void __launch_bounds__(256)
init_logits(const float* __restrict__ b2, float* __restrict__ out) {
    int i = blockIdx.x * 256 + threadIdx.x;
    if (i < B_ * C_) out[i] = 100.0f * b2[i & (C_ - 1)];
}

__global__ void __launch_bounds__(256)
snn_fused(const float* __restrict__ x, const float* __restrict__ W1,
          const float* __restrict__ b1, const float* __restrict__ W2,
          float* __restrict__ logits) {
    __shared__ SM sm;
    const int tid = threadIdx.x;
    const int tx = tid & 15;        // micro-tile row group
    const int ty = tid >> 4;        // micro-tile col group
    const int blk = blockIdx.x;
    const int bb = blk >> 3;        // batch block 0..31
    const int h0 = (blk & 7) * NT;  // h tile offset

    // --- staging thread mapping: 2 threads per tile row, 2x float4 along k ---
    const int sr = tid >> 1;         // tile row / W1 row index 0..127
    const int kb = (tid & 1) * 8;    // k sub-offset 0 or 8
    const int bi_s = sr >> 4;        // batch-in-block of staged A row
    const int tloc = sr & 15;        // t-in-chunk of staged A row
    const float* abase = x + ((long)(bb * BB + bi_s) * T_) * I_;
    const float* bbase = W1 + (long)(h0 + sr) * I_;

    // --- scan thread mapping: wave w owns batch-in-block w (lower) / w+4 (upper) ---
    const int bi_lo = tid >> 6;      // 0..3, wave-uniform
    const int hA = tid & 63;
    const int hB = hA + 64;

    float mem[4] = {0.f, 0.f, 0.f, 0.f};   // [loA, loB, hiA, hiB]
    float ss[4]  = {0.f, 0.f, 0.f, 0.f};

    // b1 per accumulator column (added when writing cur tile)
    float bcol[8];
#pragma unroll
    for (int j = 0; j < 8; ++j) {
        int col = (j < 4) ? (ty * 4 + j) : (64 + ty * 4 + (j - 4));
        bcol[j] = b1[h0 + col];
    }

    for (int chunk = 0; chunk < NCHUNK; ++chunk) {
        const int t0 = chunk * TC;
        const int tv = min(TC, T_ - t0);
        const bool avalid = (t0 + tloc) < T_;
        const float* aptr = abase + (long)(t0 + tloc) * I_;

        float4 ar0, ar1, br0, br1;
        // prefetch k0 = 0
        if (avalid) {
            ar0 = *(const float4*)(aptr + kb);
            ar1 = *(const float4*)(aptr + kb + 4);
        } else {
            ar0 = make_float4(0.f, 0.f, 0.f, 0.f);
            ar1 = make_float4(0.f, 0.f, 0.f, 0.f);
        }
        br0 = *(const float4*)(bbase + kb);
        br1 = *(const float4*)(bbase + kb + 4);

        float acc[8][8];
#pragma unroll
        for (int i = 0; i < 8; ++i)
#pragma unroll
            for (int j = 0; j < 8; ++j) acc[i][j] = 0.f;

        for (int k0 = 0; k0 < I_; k0 += KB) {
            __syncthreads();   // prior LDS consumers (FMA reads / scan) done
#pragma unroll
            for (int j = 0; j < 4; ++j) {
                sm.s.As[kb + j][sr]     = ((const float*)&ar0)[j];
                sm.s.As[kb + 4 + j][sr] = ((const float*)&ar1)[j];
                sm.s.Bs[kb + j][sr]     = ((const float*)&br0)[j];
                sm.s.Bs[kb + 4 + j][sr] = ((const float*)&br1)[j];
            }
            __syncthreads();
            if (k0 + KB < I_) {   // prefetch next k-slice into registers
                const int kn = k0 + KB;
                if (avalid) {
                    ar0 = *(const float4*)(aptr + kn + kb);
                    ar1 = *(const float4*)(aptr + kn + kb + 4);
                }
                br0 = *(const float4*)(bbase + kn + kb);
                br1 = *(const float4*)(bbase + kn + kb + 4);
            }
#pragma unroll
            for (int kk = 0; kk < KB; ++kk) {
                float4 a0  = *(const float4*)&sm.s.As[kk][tx * 4];
                float4 a1  = *(const float4*)&sm.s.As[kk][64 + tx * 4];
                float4 b0  = *(const float4*)&sm.s.Bs[kk][ty * 4];
                float4 b1v = *(const float4*)&sm.s.Bs[kk][64 + ty * 4];
                float av[8] = {a0.x, a0.y, a0.z, a0.w, a1.x, a1.y, a1.z, a1.w};
                float bv[8] = {b0.x, b0.y, b0.z, b0.w, b1v.x, b1v.y, b1v.z, b1v.w};
#pragma unroll
                for (int i = 0; i < 8; ++i)
#pragma unroll
                    for (int j = 0; j < 8; ++j)
                        acc[i][j] = fmaf(av[i], bv[j], acc[i][j]);
            }
        }

        // ---- lower half (global rows 0..63 = batches bi 0..3) ----
        __syncthreads();   // FMA reads done; LDS now reusable as Cs
#pragma unroll
        for (int i = 0; i < 4; ++i) {
            float4 lo = make_float4(acc[i][0] + bcol[0], acc[i][1] + bcol[1],
                                    acc[i][2] + bcol[2], acc[i][3] + bcol[3]);
            float4 hi = make_float4(acc[i][4] + bcol[4], acc[i][5] + bcol[5],
                                    acc[i][6] + bcol[6], acc[i][7] + bcol[7]);
            *(float4*)&sm.Cs[tx * 4 + i][ty * 4]      = lo;
            *(float4*)&sm.Cs[tx * 4 + i][64 + ty * 4] = hi;
        }
        __syncthreads();
        for (int t = 0; t < tv; ++t) {
            float c1 = sm.Cs[bi_lo * 16 + t][hA];
            float c2 = sm.Cs[bi_lo * 16 + t][hB];
            lif_step(mem[0], ss[0], c1);
            lif_step(mem[1], ss[1], c2);
        }

        // ---- upper half (global rows 64..127 = batches bi 4..7) ----
        __syncthreads();
#pragma unroll
        for (int i = 4; i < 8; ++i) {
            float4 lo = make_float4(acc[i][0] + bcol[0], acc[i][1] + bcol[1],
                                    acc[i][2] + bcol[2], acc[i][3] + bcol[3]);
            float4 hi = make_float4(acc[i][4] + bcol[4], acc[i][5] + bcol[5],
                                    acc[i][6] + bcol[6], acc[i][7] + bcol[7]);
            *(float4*)&sm.Cs[tx * 4 + (i - 4)][ty * 4]      = lo;
            *(float4*)&sm.Cs[tx * 4 + (i - 4)][64 + ty * 4] = hi;
        }
        __syncthreads();
        for (int t = 0; t < tv; ++t) {
            float c1 = sm.Cs[bi_lo * 16 + t][hA];
            float c2 = sm.Cs[bi_lo * 16 + t][hB];
            lif_step(mem[2], ss[2], c1);
            lif_step(mem[3], ss[3], c2);
        }
    }

    // ---- epilogue: logits[b,c] += sum_h ss[b,h] * W2[c,h] (wave reduce + atomic) ----
#pragma unroll
    for (int c = 0; c < C_; ++c) {
        float v = ss[0] * W2[c * H_ + h0 + hA] + ss[1] * W2[c * H_ + h0 + hB];
#pragma unroll
        for (int off = 32; off > 0; off >>= 1) v += __shfl_down(v, off, 64);
        if (hA == 0) atomicAdd(&logits[(bb * BB + bi_lo) * C_ + c], v);
    }
#pragma unroll
    for (int c = 0; c < C_; ++c) {
        float v = ss[2] * W2[c * H_ + h0 + hA] + ss[3] * W2[c * H_ + h0 + hB];
#pragma unroll
        for (int off = 32; off > 0; off >>= 1) v += __shfl_down(v, off, 64);
        if (hA == 0) atomicAdd(&logits[(bb * BB + bi_lo + 4) * C_ + c], v);
    }
}

extern "C" void kernel_launch(void* const* d_in, const int* in_sizes, int n_in,
                              void* d_out, int out_size, void* d_ws, size_t ws_size,
                              hipStream_t stream) {
    const float* x  = (const float*)d_in[0];
    const float* W1 = (const float*)d_in[1];
    const float* b1 = (const float*)d_in[2];
    const float* W2 = (const float*)d_in[3];
    const float* b2 = (const float*)d_in[4];
    float* out = (float*)d_out;

    hipLaunchKernelGGL(init_logits, dim3((B_ * C_ + 255) / 256), dim3(256), 0, stream,
                       b2, out);
    hipLaunchKernelGGL(snn_fused, dim3((B_ / BB) * (H_ / NT)), dim3(256), 0, stream,
                       x, W1, b1, W2, out);
}

// Round 2
// 247.247 us; speedup vs baseline: 2.9608x; 2.9608x over previous
//
#include <hip/hip_runtime.h>

// SNN direction decoder via f16 split-GEMM on matrix cores.
// B=256, T=100, I=512, H=1024, C=8.
// Pipeline: init_logits | split_x | split_w | gemm_f16 (MFMA) | scan_fc2.
// fp32 GEMM emulated as 3-term f16 GEMM: x*w ~= xh*wh + xh*wl + xl*wh,
// inputs pre-scaled by 2^6 so lo-parts avoid f16 subnormal flush; epilogue
// un-scales by 2^-12. K' = 3*512 = 1536.

#define B_   256
#define T_   100
#define I_   512
#define H_   1024
#define C_   8
#define M_   (B_ * T_)        // 25600
#define KP   1536             // split K'
#define SC   64.0f            // 2^6 pre-scale
#define ISC  (1.0f / 4096.0f) // 2^-12 epilogue un-scale

typedef _Float16 half8 __attribute__((ext_vector_type(8)));
typedef _Float16 half4 __attribute__((ext_vector_type(4)));
typedef float floatx4 __attribute__((ext_vector_type(4)));

__device__ __forceinline__ void ld_g2l(const _Float16* g, _Float16* l) {
    // async global->LDS, 16B/lane; LDS dest = wave-uniform base + lane*16
    __builtin_amdgcn_global_load_lds(
        (const __attribute__((address_space(1))) void*)g,
        (__attribute__((address_space(3))) void*)l, 16, 0, 0);
}

__global__ void __launch_bounds__(256)
init_logits(const float* __restrict__ b2, float* __restrict__ out) {
    int i = blockIdx.x * 256 + threadIdx.x;
    if (i < B_ * C_) out[i] = 100.0f * b2[i & (C_ - 1)];
}

// x[M][512] fp32 -> A[M][1536] f16 = [xh | xh | xl], scaled by 2^6
__global__ void __launch_bounds__(256)
split_x(const float* __restrict__ x, _Float16* __restrict__ A) {
    int g = blockIdx.x * 256 + threadIdx.x;   // M*128 threads, 4 elems each
    int i0 = (g & 127) * 4;
    int m = g >> 7;
    float4 v = *(const float4*)(x + (size_t)m * I_ + i0);
    float vv[4] = {v.x, v.y, v.z, v.w};
    half4 hi, lo;
#pragma unroll
    for (int j = 0; j < 4; ++j) {
        float s = vv[j] * SC;
        _Float16 h = (_Float16)s;
        hi[j] = h;
        lo[j] = (_Float16)(s - (float)h);
    }
    _Float16* r = A + (size_t)m * KP + i0;
    *(half4*)(r) = hi;
    *(half4*)(r + 512) = hi;
    *(half4*)(r + 1024) = lo;
}

// W1[H][512] fp32 -> Wp[H][1536] f16 = [wh | wl | wh], scaled by 2^6
__global__ void __launch_bounds__(256)
split_w(const float* __restrict__ w, _Float16* __restrict__ Wp) {
    int g = blockIdx.x * 256 + threadIdx.x;   // H*128 threads
    int i0 = (g & 127) * 4;
    int h = g >> 7;
    float4 v = *(const float4*)(w + (size_t)h * I_ + i0);
    float vv[4] = {v.x, v.y, v.z, v.w};
    half4 hi, lo;
#pragma unroll
    for (int j = 0; j < 4; ++j) {
        float s = vv[j] * SC;
        _Float16 hh = (_Float16)s;
        hi[j] = hh;
        lo[j] = (_Float16)(s - (float)hh);
    }
    _Float16* r = Wp + (size_t)h * KP + i0;
    *(half4*)(r) = hi;
    *(half4*)(r + 512) = lo;
    *(half4*)(r + 1024) = hi;
}

// C[M][H] = A[M][KP] * Wp[H][KP]^T ; 128x128 tile, 16x16x32 f16 MFMA,
// global_load_lds staging, XOR-swizzled LDS (conflict-free ds_read_b128).
__global__ void __launch_bounds__(256)
gemm_f16(const _Float16* __restrict__ A, const _Float16* __restrict__ Wp,
         const float* __restrict__ b1, float* __restrict__ cur) {
    __shared__ __align__(16) _Float16 As[128 * 64];
    __shared__ __align__(16) _Float16 Bs[128 * 64];
    const int tid = threadIdx.x;
    const int lane = tid & 63;
    const int w = tid >> 6;
    const int m0 = (blockIdx.x >> 3) * 128;
    const int n0 = (blockIdx.x & 7) * 128;
    const int wm = (w >> 1) * 64;   // wave's 64x64 sub-tile
    const int wn = (w & 1) * 64;

    // staging: wave w covers rows [w*32, w*32+32) of each tile, 4 instrs x 8 rows
    const int srow = lane >> 3;               // 0..7 within instr
    const int sc16 = (lane & 7) ^ srow;       // XOR swizzle: logical k16 fetched
    const _Float16* ag = A + (size_t)(m0 + w * 32 + srow) * KP + sc16 * 8;
    const _Float16* bg = Wp + (size_t)(n0 + w * 32 + srow) * KP + sc16 * 8;
    _Float16* al = &As[(w * 32) * 64];
    _Float16* bl = &Bs[(w * 32) * 64];

    floatx4 acc[4][4];
#pragma unroll
    for (int i = 0; i < 4; ++i)
#pragma unroll
        for (int j = 0; j < 4; ++j) acc[i][j] = (floatx4){0.f, 0.f, 0.f, 0.f};

    const int quad = lane >> 4;
    const int l15 = lane & 15;
    const int l7 = lane & 7;

    for (int kt = 0; kt < KP / 64; ++kt) {
        const int ko = kt * 64;
        __syncthreads();
#pragma unroll
        for (int j = 0; j < 4; ++j) {
            ld_g2l(ag + ko + j * (8 * KP), al + j * (8 * 64));
            ld_g2l(bg + ko + j * (8 * KP), bl + j * (8 * 64));
        }
        __syncthreads();
#pragma unroll
        for (int ks = 0; ks < 2; ++ks) {
            half8 av[4], bv[4];
#pragma unroll
            for (int f = 0; f < 4; ++f) {
                const int c16 = (ks * 4 + quad) ^ l7;   // physical (swizzled) k16
                av[f] = *(const half8*)&As[(wm + f * 16 + l15) * 64 + c16 * 8];
                bv[f] = *(const half8*)&Bs[(wn + f * 16 + l15) * 64 + c16 * 8];
            }
#pragma unroll
            for (int fr = 0; fr < 4; ++fr)
#pragma unroll
                for (int fn = 0; fn < 4; ++fn)
                    acc[fr][fn] = __builtin_amdgcn_mfma_f32_16x16x32_f16(
                        av[fr], bv[fn], acc[fr][fn], 0, 0, 0);
        }
    }

    // epilogue: C/D layout col=lane&15, row=quad*4+reg
    float b1c[4];
#pragma unroll
    for (int fn = 0; fn < 4; ++fn) b1c[fn] = b1[n0 + wn + fn * 16 + l15];
#pragma unroll
    for (int fr = 0; fr < 4; ++fr) {
        const int mrow = m0 + wm + fr * 16 + quad * 4;
#pragma unroll
        for (int r = 0; r < 4; ++r) {
            float* op = cur + (size_t)(mrow + r) * H_ + n0 + wn + l15;
#pragma unroll
            for (int fn = 0; fn < 4; ++fn)
                op[fn * 16] = acc[fr][fn][r] * ISC + b1c[fn];
        }
    }
}

// LIF scan over t + FC2 reduce. One block = (batch b, 256 h's).
__global__ void __launch_bounds__(256)
scan_fc2(const float* __restrict__ cur, const float* __restrict__ W2,
         float* __restrict__ logits) {
    const int tid = threadIdx.x;
    const int b = blockIdx.x >> 2;
    const int h = (blockIdx.x & 3) * 256 + tid;
    const float* p = cur + (size_t)b * T_ * H_ + h;
    float mem = 0.f, ss = 0.f;
#pragma unroll 4
    for (int t = 0; t < T_; ++t) {
        float c = p[(size_t)t * H_];
        float reset = (mem > 1.0f) ? 1.0f : 0.0f;
        mem = 0.9f * mem + c - reset;
        ss += (mem > 1.0f) ? 1.0f : 0.0f;
    }
    __shared__ float part[C_][4];
    const int wid = tid >> 6, lane = tid & 63;
#pragma unroll
    for (int c = 0; c < C_; ++c) {
        float v = ss * W2[c * H_ + h];
#pragma unroll
        for (int off = 32; off; off >>= 1) v += __shfl_down(v, off, 64);
        if (lane == 0) part[c][wid] = v;
    }
    __syncthreads();
    if (tid < C_) {
        float s = part[tid][0] + part[tid][1] + part[tid][2] + part[tid][3];
        atomicAdd(&logits[b * C_ + tid], s);
    }
}

extern "C" void kernel_launch(void* const* d_in, const int* in_sizes, int n_in,
                              void* d_out, int out_size, void* d_ws, size_t ws_size,
                              hipStream_t stream) {
    const float* x  = (const float*)d_in[0];
    const float* W1 = (const float*)d_in[1];
    const float* b1 = (const float*)d_in[2];
    const float* W2 = (const float*)d_in[3];
    const float* b2 = (const float*)d_in[4];
    float* out = (float*)d_out;

    // workspace layout
    char* ws = (char*)d_ws;
    _Float16* Asp = (_Float16*)ws;                              // 78,643,200 B
    _Float16* Wsp = (_Float16*)(ws + 78643200);                 //  3,145,728 B
    float* cur    = (float*)(ws + 78643200 + 3145728);          // 104,857,600 B

    hipLaunchKernelGGL(init_logits, dim3(8), dim3(256), 0, stream, b2, out);
    hipLaunchKernelGGL(split_x, dim3(M_ * 128 / 256), dim3(256), 0, stream, x, Asp);
    hipLaunchKernelGGL(split_w, dim3(H_ * 128 / 256), dim3(256), 0, stream, W1, Wsp);
    hipLaunchKernelGGL(gemm_f16, dim3((M_ / 128) * (H_ / 128)), dim3(256), 0, stream,
                       Asp, Wsp, b1, cur);
    hipLaunchKernelGGL(scan_fc2, dim3(B_ * 4), dim3(256), 0, stream, cur, W2, out);
}

// Round 3
// 230.156 us; speedup vs baseline: 3.1807x; 1.0743x over previous
//
#include <hip/hip_runtime.h>

// SNN direction decoder via f16 split-GEMM on matrix cores.
// B=256, T=100, I=512, H=1024, C=8.
// Pipeline: init_logits | split_x | split_w | gemm_f16 (MFMA) | scan_fc2.
// fp32 GEMM emulated as 3-term f16 GEMM: x*w ~= xh*wh + xh*wl + xl*wh,
// inputs pre-scaled by 2^6 so lo-parts avoid f16 subnormal flush; epilogue
// un-scales by 2^-12. K' = 3*512 = 1536.
//
// R3: XCD-aware block swizzle in gemm_f16 — XCD c (= blk%8) exclusively owns
// m-tiles [25c,25c+25), 8 n-variants of one m-tile adjacent in dispatch order
// on that XCD -> A tile fetched from HBM once, 7 L2 hits (was: 8 XCD misses).

#define B_   256
#define T_   100
#define I_   512
#define H_   1024
#define C_   8
#define M_   (B_ * T_)        // 25600
#define KP   1536             // split K'
#define SC   64.0f            // 2^6 pre-scale
#define ISC  (1.0f / 4096.0f) // 2^-12 epilogue un-scale

typedef _Float16 half8 __attribute__((ext_vector_type(8)));
typedef _Float16 half4 __attribute__((ext_vector_type(4)));
typedef float floatx4 __attribute__((ext_vector_type(4)));

__device__ __forceinline__ void ld_g2l(const _Float16* g, _Float16* l) {
    // async global->LDS, 16B/lane; LDS dest = wave-uniform base + lane*16
    __builtin_amdgcn_global_load_lds(
        (const __attribute__((address_space(1))) void*)g,
        (__attribute__((address_space(3))) void*)l, 16, 0, 0);
}

__global__ void __launch_bounds__(256)
init_logits(const float* __restrict__ b2, float* __restrict__ out) {
    int i = blockIdx.x * 256 + threadIdx.x;
    if (i < B_ * C_) out[i] = 100.0f * b2[i & (C_ - 1)];
}

// x[M][512] fp32 -> A[M][1536] f16 = [xh | xh | xl], scaled by 2^6
__global__ void __launch_bounds__(256)
split_x(const float* __restrict__ x, _Float16* __restrict__ A) {
    int g = blockIdx.x * 256 + threadIdx.x;   // M*128 threads, 4 elems each
    int i0 = (g & 127) * 4;
    int m = g >> 7;
    float4 v = *(const float4*)(x + (size_t)m * I_ + i0);
    float vv[4] = {v.x, v.y, v.z, v.w};
    half4 hi, lo;
#pragma unroll
    for (int j = 0; j < 4; ++j) {
        float s = vv[j] * SC;
        _Float16 h = (_Float16)s;
        hi[j] = h;
        lo[j] = (_Float16)(s - (float)h);
    }
    _Float16* r = A + (size_t)m * KP + i0;
    *(half4*)(r) = hi;
    *(half4*)(r + 512) = hi;
    *(half4*)(r + 1024) = lo;
}

// W1[H][512] fp32 -> Wp[H][1536] f16 = [wh | wl | wh], scaled by 2^6
__global__ void __launch_bounds__(256)
split_w(const float* __restrict__ w, _Float16* __restrict__ Wp) {
    int g = blockIdx.x * 256 + threadIdx.x;   // H*128 threads
    int i0 = (g & 127) * 4;
    int h = g >> 7;
    float4 v = *(const float4*)(w + (size_t)h * I_ + i0);
    float vv[4] = {v.x, v.y, v.z, v.w};
    half4 hi, lo;
#pragma unroll
    for (int j = 0; j < 4; ++j) {
        float s = vv[j] * SC;
        _Float16 hh = (_Float16)s;
        hi[j] = hh;
        lo[j] = (_Float16)(s - (float)hh);
    }
    _Float16* r = Wp + (size_t)h * KP + i0;
    *(half4*)(r) = hi;
    *(half4*)(r + 512) = lo;
    *(half4*)(r + 1024) = hi;
}

// C[M][H] = A[M][KP] * Wp[H][KP]^T ; 128x128 tile, 16x16x32 f16 MFMA,
// global_load_lds staging, XOR-swizzled LDS (conflict-free ds_read_b128).
__global__ void __launch_bounds__(256)
gemm_f16(const _Float16* __restrict__ A, const _Float16* __restrict__ Wp,
         const float* __restrict__ b1, float* __restrict__ cur) {
    __shared__ __align__(16) _Float16 As[128 * 64];
    __shared__ __align__(16) _Float16 Bs[128 * 64];
    const int tid = threadIdx.x;
    const int lane = tid & 63;
    const int w = tid >> 6;

    // --- XCD-aware swizzle: xcd = blk % 8 owns m-band [25*xcd, 25*xcd+25),
    //     the 8 n-variants of an m-tile are consecutive on that XCD.
    const int xcd = blockIdx.x & 7;
    const int j = blockIdx.x >> 3;          // 0..199, per-XCD sequence
    const int m_idx = xcd * 25 + (j >> 3);  // 0..199
    const int n_idx = j & 7;                // 0..7
    const int m0 = m_idx * 128;
    const int n0 = n_idx * 128;

    const int wm = (w >> 1) * 64;   // wave's 64x64 sub-tile
    const int wn = (w & 1) * 64;

    // staging: wave w covers rows [w*32, w*32+32) of each tile, 4 instrs x 8 rows
    const int srow = lane >> 3;               // 0..7 within instr
    const int sc16 = (lane & 7) ^ srow;       // XOR swizzle: logical k16 fetched
    const _Float16* ag = A + (size_t)(m0 + w * 32 + srow) * KP + sc16 * 8;
    const _Float16* bg = Wp + (size_t)(n0 + w * 32 + srow) * KP + sc16 * 8;
    _Float16* al = &As[(w * 32) * 64];
    _Float16* bl = &Bs[(w * 32) * 64];

    floatx4 acc[4][4];
#pragma unroll
    for (int i = 0; i < 4; ++i)
#pragma unroll
        for (int jj = 0; jj < 4; ++jj) acc[i][jj] = (floatx4){0.f, 0.f, 0.f, 0.f};

    const int quad = lane >> 4;
    const int l15 = lane & 15;
    const int l7 = lane & 7;

    for (int kt = 0; kt < KP / 64; ++kt) {
        const int ko = kt * 64;
        __syncthreads();
#pragma unroll
        for (int jj = 0; jj < 4; ++jj) {
            ld_g2l(ag + ko + jj * (8 * KP), al + jj * (8 * 64));
            ld_g2l(bg + ko + jj * (8 * KP), bl + jj * (8 * 64));
        }
        __syncthreads();
#pragma unroll
        for (int ks = 0; ks < 2; ++ks) {
            half8 av[4], bv[4];
#pragma unroll
            for (int f = 0; f < 4; ++f) {
                const int c16 = (ks * 4 + quad) ^ l7;   // physical (swizzled) k16
                av[f] = *(const half8*)&As[(wm + f * 16 + l15) * 64 + c16 * 8];
                bv[f] = *(const half8*)&Bs[(wn + f * 16 + l15) * 64 + c16 * 8];
            }
#pragma unroll
            for (int fr = 0; fr < 4; ++fr)
#pragma unroll
                for (int fn = 0; fn < 4; ++fn)
                    acc[fr][fn] = __builtin_amdgcn_mfma_f32_16x16x32_f16(
                        av[fr], bv[fn], acc[fr][fn], 0, 0, 0);
        }
    }

    // epilogue: C/D layout col=lane&15, row=quad*4+reg
    float b1c[4];
#pragma unroll
    for (int fn = 0; fn < 4; ++fn) b1c[fn] = b1[n0 + wn + fn * 16 + l15];
#pragma unroll
    for (int fr = 0; fr < 4; ++fr) {
        const int mrow = m0 + wm + fr * 16 + quad * 4;
#pragma unroll
        for (int r = 0; r < 4; ++r) {
            float* op = cur + (size_t)(mrow + r) * H_ + n0 + wn + l15;
#pragma unroll
            for (int fn = 0; fn < 4; ++fn)
                op[fn * 16] = acc[fr][fn][r] * ISC + b1c[fn];
        }
    }
}

// LIF scan over t + FC2 reduce. One block = (batch b, 256 h's).
__global__ void __launch_bounds__(256)
scan_fc2(const float* __restrict__ cur, const float* __restrict__ W2,
         float* __restrict__ logits) {
    const int tid = threadIdx.x;
    const int b = blockIdx.x >> 2;
    const int h = (blockIdx.x & 3) * 256 + tid;
    const float* p = cur + (size_t)b * T_ * H_ + h;
    float mem = 0.f, ss = 0.f;
#pragma unroll 10
    for (int t = 0; t < T_; ++t) {
        float c = p[(size_t)t * H_];
        float reset = (mem > 1.0f) ? 1.0f : 0.0f;
        mem = 0.9f * mem + c - reset;
        ss += (mem > 1.0f) ? 1.0f : 0.0f;
    }
    __shared__ float part[C_][4];
    const int wid = tid >> 6, lane = tid & 63;
#pragma unroll
    for (int c = 0; c < C_; ++c) {
        float v = ss * W2[c * H_ + h];
#pragma unroll
        for (int off = 32; off; off >>= 1) v += __shfl_down(v, off, 64);
        if (lane == 0) part[c][wid] = v;
    }
    __syncthreads();
    if (tid < C_) {
        float s = part[tid][0] + part[tid][1] + part[tid][2] + part[tid][3];
        atomicAdd(&logits[b * C_ + tid], s);
    }
}

extern "C" void kernel_launch(void* const* d_in, const int* in_sizes, int n_in,
                              void* d_out, int out_size, void* d_ws, size_t ws_size,
                              hipStream_t stream) {
    const float* x  = (const float*)d_in[0];
    const float* W1 = (const float*)d_in[1];
    const float* b1 = (const float*)d_in[2];
    const float* W2 = (const float*)d_in[3];
    const float* b2 = (const float*)d_in[4];
    float* out = (float*)d_out;

    // workspace layout
    char* ws = (char*)d_ws;
    _Float16* Asp = (_Float16*)ws;                              // 78,643,200 B
    _Float16* Wsp = (_Float16*)(ws + 78643200);                 //  3,145,728 B
    float* cur    = (float*)(ws + 78643200 + 3145728);          // 104,857,600 B

    hipLaunchKernelGGL(init_logits, dim3(8), dim3(256), 0, stream, b2, out);
    hipLaunchKernelGGL(split_x, dim3(M_ * 128 / 256), dim3(256), 0, stream, x, Asp);
    hipLaunchKernelGGL(split_w, dim3(H_ * 128 / 256), dim3(256), 0, stream, W1, Wsp);
    hipLaunchKernelGGL(gemm_f16, dim3((M_ / 128) * (H_ / 128)), dim3(256), 0, stream,
                       Asp, Wsp, b1, cur);
    hipLaunchKernelGGL(scan_fc2, dim3(B_ * 4), dim3(256), 0, stream, cur, W2, out);
}

// Round 4
// 210.045 us; speedup vs baseline: 3.4852x; 1.0957x over previous
//
#include <hip/hip_runtime.h>

// SNN direction decoder — fused MFMA GEMM + LIF scan + FC2.
// B=256, T=100, I=512, H=1024, C=8.
// Pipeline: split_x | split_w_init | snn_mfma (fused).
// fp32 GEMM emulated as 3-term f16 GEMM (xh*wh + xh*wl + xl*wh), inputs
// pre-scaled by 2^6, un-scaled 2^-12 at epilogue. Stored splits are
// non-duplicated [hi|lo] (1024 wide); k-tile remap reads xh twice (L2-hot).
// Fused block = (batch b, 128-h tile): M-tile = t 0..127 (100 valid) of one
// batch -> after K-loop, acc -> LDS (two 64-row phases) -> per-(b,h) serial
// LIF scan in threads 0..127 -> wave-reduce FC2 -> atomicAdd logits.

#define B_   256
#define T_   100
#define I_   512
#define H_   1024
#define C_   8
#define M_   (B_ * T_)        // 25600
#define KS_  1024             // stored split width [hi|lo]
#define SC   64.0f            // 2^6 pre-scale
#define ISC  (1.0f / 4096.0f) // 2^-12 epilogue un-scale
#define CP   132              // Cs row pitch (floats): quad offsets hit banks {0,16}

typedef _Float16 half8 __attribute__((ext_vector_type(8)));
typedef _Float16 half4 __attribute__((ext_vector_type(4)));
typedef float floatx4 __attribute__((ext_vector_type(4)));

__device__ __forceinline__ void ld_g2l(const _Float16* g, _Float16* l) {
    // async global->LDS, 16B/lane; LDS dest = wave-uniform base + lane*16
    __builtin_amdgcn_global_load_lds(
        (const __attribute__((address_space(1))) void*)g,
        (__attribute__((address_space(3))) void*)l, 16, 0, 0);
}

// x[M][512] fp32 -> Asp[M][1024] f16 = [xh | xl], scaled by 2^6
__global__ void __launch_bounds__(256)
split_x(const float* __restrict__ x, _Float16* __restrict__ A) {
    int g = blockIdx.x * 256 + threadIdx.x;   // M*128 threads, 4 elems each
    int i0 = (g & 127) * 4;
    int m = g >> 7;
    float4 v = *(const float4*)(x + (size_t)m * I_ + i0);
    float vv[4] = {v.x, v.y, v.z, v.w};
    half4 hi, lo;
#pragma unroll
    for (int j = 0; j < 4; ++j) {
        float s = vv[j] * SC;
        _Float16 h = (_Float16)s;
        hi[j] = h;
        lo[j] = (_Float16)(s - (float)h);
    }
    _Float16* r = A + (size_t)m * KS_ + i0;
    *(half4*)(r) = hi;
    *(half4*)(r + 512) = lo;
}

// W1[H][512] fp32 -> Wsp[H][1024] f16 = [wh | wl]; blocks 0..7 also init logits
__global__ void __launch_bounds__(256)
split_w_init(const float* __restrict__ w, _Float16* __restrict__ Wp,
             const float* __restrict__ b2, float* __restrict__ out) {
    int g = blockIdx.x * 256 + threadIdx.x;   // H*128 threads (512 blocks)
    if (g < B_ * C_) out[g] = 100.0f * b2[g & (C_ - 1)];
    int i0 = (g & 127) * 4;
    int h = g >> 7;
    float4 v = *(const float4*)(w + (size_t)h * I_ + i0);
    float vv[4] = {v.x, v.y, v.z, v.w};
    half4 hi, lo;
#pragma unroll
    for (int j = 0; j < 4; ++j) {
        float s = vv[j] * SC;
        _Float16 hh = (_Float16)s;
        hi[j] = hh;
        lo[j] = (_Float16)(s - (float)hh);
    }
    _Float16* r = Wp + (size_t)h * KS_ + i0;
    *(half4*)(r) = hi;
    *(half4*)(r + 512) = lo;
}

// Fused: C-tile[t 0..127][128 h] via 24 k-tiles (segments xh*wh, xh*wl, xl*wh),
// then LIF scan + FC2. XCD-swizzled: xcd=blk&7 owns batches [32*xcd, 32*xcd+32).
__global__ void __launch_bounds__(256, 4)
snn_mfma(const _Float16* __restrict__ Asp, const _Float16* __restrict__ Wsp,
         const float* __restrict__ b1, const float* __restrict__ W2,
         float* __restrict__ logits) {
    __shared__ union {
        struct { __align__(16) _Float16 A[128 * 64]; __align__(16) _Float16 Bm[128 * 64]; } g;
        float Cs[64 * CP];
    } sm;
    const int tid = threadIdx.x;
    const int lane = tid & 63;
    const int w = tid >> 6;

    const int xcd = blockIdx.x & 7;
    const int jj = blockIdx.x >> 3;        // 0..255 per-XCD sequence
    const int b  = xcd * 32 + (jj >> 3);   // batch 0..255
    const int n0 = (jj & 7) * 128;         // h tile offset

    const int wm = (w >> 1) * 64;   // wave's 64x64 sub-tile
    const int wn = (w & 1) * 64;
    const int srow = lane >> 3;
    const int sc16 = (lane & 7) ^ srow;    // XOR swizzle (matches read side)

    // staging pointers: wave w stages tile rows [32w, 32w+32), 4 instrs x 8 rows.
    // A row r -> m = b*100 + r (r up to 127 overreads into next batch / Wsp: masked in scan)
    const _Float16* ag[4];
    const _Float16* bg[4];
    _Float16* al[4];
    _Float16* bl[4];
#pragma unroll
    for (int j = 0; j < 4; ++j) {
        const int r = w * 32 + j * 8 + srow;
        ag[j] = Asp + ((size_t)b * T_ + r) * KS_ + sc16 * 8;
        bg[j] = Wsp + (size_t)(n0 + r) * KS_ + sc16 * 8;
        al[j] = &sm.g.A[(w * 32 + j * 8) * 64];
        bl[j] = &sm.g.Bm[(w * 32 + j * 8) * 64];
    }

    floatx4 acc[4][4];
#pragma unroll
    for (int i = 0; i < 4; ++i)
#pragma unroll
        for (int q = 0; q < 4; ++q) acc[i][q] = (floatx4){0.f, 0.f, 0.f, 0.f};

    const int quad = lane >> 4;
    const int l15 = lane & 15;
    const int l7 = lane & 7;

    for (int kt = 0; kt < 24; ++kt) {
        // segment map: kt 0..7 xh*wh, 8..15 xh*wl, 16..23 xl*wh
        const int koA = ((kt & 16) ? 512 : 0) + (kt & 7) * 64;
        const int koB = ((kt & 8)  ? 512 : 0) + (kt & 7) * 64;
        __syncthreads();
#pragma unroll
        for (int j = 0; j < 4; ++j) {
            ld_g2l(ag[j] + koA, al[j]);
            ld_g2l(bg[j] + koB, bl[j]);
        }
        __syncthreads();
#pragma unroll
        for (int ks = 0; ks < 2; ++ks) {
            half8 av[4], bv[4];
#pragma unroll
            for (int f = 0; f < 4; ++f) {
                const int c16 = (ks * 4 + quad) ^ l7;   // physical (swizzled) k16
                av[f] = *(const half8*)&sm.g.A[(wm + f * 16 + l15) * 64 + c16 * 8];
                bv[f] = *(const half8*)&sm.g.Bm[(wn + f * 16 + l15) * 64 + c16 * 8];
            }
#pragma unroll
            for (int fr = 0; fr < 4; ++fr)
#pragma unroll
                for (int fn = 0; fn < 4; ++fn)
                    acc[fr][fn] = __builtin_amdgcn_mfma_f32_16x16x32_f16(
                        av[fr], bv[fn], acc[fr][fn], 0, 0, 0);
        }
    }

    // ---- epilogue: acc -> LDS (two 64-row phases) -> serial LIF scan ----
    float b1c[4];
#pragma unroll
    for (int fn = 0; fn < 4; ++fn) b1c[fn] = b1[n0 + wn + fn * 16 + l15];

    float mem = 0.f, ss = 0.f;
    const int myh = tid & 127;     // scan column for threads 0..127

    __syncthreads();               // all k-loop ds_reads done before overwrite
    // phase A: waves 0,1 (wm=0) hold C rows 0..63 = t 0..63
    if (w < 2) {
#pragma unroll
        for (int fr = 0; fr < 4; ++fr)
#pragma unroll
            for (int r = 0; r < 4; ++r) {
                float* dst = &sm.Cs[(fr * 16 + quad * 4 + r) * CP + wn + l15];
#pragma unroll
                for (int fn = 0; fn < 4; ++fn)
                    dst[fn * 16] = acc[fr][fn][r] * ISC + b1c[fn];
            }
    }
    __syncthreads();
    if (tid < 128) {
#pragma unroll 8
        for (int t = 0; t < 64; ++t) {
            float c = sm.Cs[t * CP + myh];
            float reset = (mem > 1.0f) ? 1.0f : 0.0f;
            mem = 0.9f * mem + c - reset;
            ss += (mem > 1.0f) ? 1.0f : 0.0f;
        }
    }
    __syncthreads();
    // phase B: waves 2,3 hold C rows 64..127 = t 64..127 (valid to 99)
    if (w >= 2) {
#pragma unroll
        for (int fr = 0; fr < 4; ++fr)
#pragma unroll
            for (int r = 0; r < 4; ++r) {
                float* dst = &sm.Cs[(fr * 16 + quad * 4 + r) * CP + wn + l15];
#pragma unroll
                for (int fn = 0; fn < 4; ++fn)
                    dst[fn * 16] = acc[fr][fn][r] * ISC + b1c[fn];
            }
    }
    __syncthreads();
    if (tid < 128) {
#pragma unroll 6
        for (int t = 0; t < 36; ++t) {   // t global 64..99
            float c = sm.Cs[t * CP + myh];
            float reset = (mem > 1.0f) ? 1.0f : 0.0f;
            mem = 0.9f * mem + c - reset;
            ss += (mem > 1.0f) ? 1.0f : 0.0f;
        }
        // ---- FC2: logits[b][c] += sum_h ss * W2[c][h] ----
#pragma unroll
        for (int c = 0; c < C_; ++c) {
            float v = ss * W2[c * H_ + n0 + myh];
#pragma unroll
            for (int off = 32; off; off >>= 1) v += __shfl_down(v, off, 64);
            if (lane == 0) atomicAdd(&logits[b * C_ + c], v);
        }
    }
}

extern "C" void kernel_launch(void* const* d_in, const int* in_sizes, int n_in,
                              void* d_out, int out_size, void* d_ws, size_t ws_size,
                              hipStream_t stream) {
    const float* x  = (const float*)d_in[0];
    const float* W1 = (const float*)d_in[1];
    const float* b1 = (const float*)d_in[2];
    const float* W2 = (const float*)d_in[3];
    const float* b2 = (const float*)d_in[4];
    float* out = (float*)d_out;

    // workspace: Asp [25600][1024] f16 = 52,428,800 B ; Wsp [1024][1024] f16
    // directly after (fused kernel's tail rows overread into Wsp by design).
    char* ws = (char*)d_ws;
    _Float16* Asp = (_Float16*)ws;
    _Float16* Wsp = (_Float16*)(ws + (size_t)M_ * KS_ * 2);

    hipLaunchKernelGGL(split_x, dim3(M_ * 128 / 256), dim3(256), 0, stream, x, Asp);
    hipLaunchKernelGGL(split_w_init, dim3(H_ * 128 / 256), dim3(256), 0, stream,
                       W1, Wsp, b2, out);
    hipLaunchKernelGGL(snn_mfma, dim3(B_ * 8), dim3(256), 0, stream,
                       Asp, Wsp, b1, W2, out);
}

// Round 5
// 195.178 us; speedup vs baseline: 3.7507x; 1.0762x over previous
//
#include <hip/hip_runtime.h>

// SNN direction decoder — fused MFMA GEMM + LIF scan + FC2.
// B=256, T=100, I=512, H=1024, C=8.
// Pipeline: split_all | snn_mfma (fused).
// fp32 GEMM emulated as 3-term f16 GEMM (xh*wh + xh*wl + xl*wh), inputs
// pre-scaled by 2^6, un-scaled 2^-12 at epilogue. Splits stored [hi|lo]
// (1024 wide) for both x (25600 rows) and W1 (1024 rows), contiguous.
// Fused block = (batch b, 128-h tile): M-tile = t 0..127 (100 valid) of one
// batch. R5: waves with wm=64 skip fr=3 (tile rows 112..127 = pure pad) and
// wave 3 skips staging those A rows -> 12.5% less MFMA + A-stage traffic.

#define B_   256
#define T_   100
#define I_   512
#define H_   1024
#define C_   8
#define M_   (B_ * T_)        // 25600
#define KS_  1024             // stored split width [hi|lo]
#define SC   64.0f            // 2^6 pre-scale
#define ISC  (1.0f / 4096.0f) // 2^-12 epilogue un-scale
#define CP   132              // Cs row pitch (floats)

typedef _Float16 half8 __attribute__((ext_vector_type(8)));
typedef float floatx4 __attribute__((ext_vector_type(4)));

__device__ __forceinline__ void ld_g2l(const _Float16* g, _Float16* l) {
    // async global->LDS, 16B/lane; LDS dest = wave-uniform base + lane*16
    __builtin_amdgcn_global_load_lds(
        (const __attribute__((address_space(1))) void*)g,
        (__attribute__((address_space(3))) void*)l, 16, 0, 0);
}

// Rows 0..25599: x -> Asp[row][hi|lo]; rows 25600..26623: W1 -> same buffer
// (Wsp region starts at Asp + 25600*1024). Blocks 0..7 also init logits.
__global__ void __launch_bounds__(256)
split_all(const float* __restrict__ x, const float* __restrict__ W1,
          const float* __restrict__ b2, _Float16* __restrict__ Asp,
          float* __restrict__ out) {
    int g = blockIdx.x * 256 + threadIdx.x;   // (M_+H_)*64 threads
    if (g < B_ * C_) out[g] = 100.0f * b2[g & (C_ - 1)];
    int row = g >> 6;
    int i0 = (g & 63) * 8;
    const float* src = (row < M_) ? (x + (size_t)row * I_ + i0)
                                  : (W1 + (size_t)(row - M_) * I_ + i0);
    float4 v0 = *(const float4*)(src);
    float4 v1 = *(const float4*)(src + 4);
    float vv[8] = {v0.x, v0.y, v0.z, v0.w, v1.x, v1.y, v1.z, v1.w};
    half8 hi, lo;
#pragma unroll
    for (int j = 0; j < 8; ++j) {
        float s = vv[j] * SC;
        _Float16 h = (_Float16)s;
        hi[j] = h;
        lo[j] = (_Float16)(s - (float)h);
    }
    _Float16* r = Asp + (size_t)row * KS_ + i0;
    *(half8*)(r) = hi;
    *(half8*)(r + 512) = lo;
}

// Fused: C-tile[t 0..127][128 h] via 24 k-tiles (segments xh*wh, xh*wl, xl*wh),
// then LIF scan + FC2. XCD-swizzled: xcd=blk&7 owns batches [32*xcd, 32*xcd+32).
__global__ void __launch_bounds__(256, 4)
snn_mfma(const _Float16* __restrict__ Asp, const _Float16* __restrict__ Wsp,
         const float* __restrict__ b1, const float* __restrict__ W2,
         float* __restrict__ logits) {
    __shared__ union {
        struct { __align__(16) _Float16 A[128 * 64]; __align__(16) _Float16 Bm[128 * 64]; } g;
        float Cs[64 * CP];
    } sm;
    const int tid = threadIdx.x;
    const int lane = tid & 63;
    const int w = tid >> 6;

    const int xcd = blockIdx.x & 7;
    const int jj = blockIdx.x >> 3;        // 0..255 per-XCD sequence
    const int b  = xcd * 32 + (jj >> 3);   // batch 0..255
    const int n0 = (jj & 7) * 128;         // h tile offset

    const int wm = (w >> 1) * 64;   // wave's 64x64 sub-tile
    const int wn = (w & 1) * 64;
    const int srow = lane >> 3;
    const int sc16 = (lane & 7) ^ srow;    // XOR swizzle (matches read side)

    // staging: wave w stages tile rows [32w, 32w+32), 4 instrs x 8 rows.
    // A row r -> m = b*100 + r (overread into next batch / Wsp: masked in scan).
    // Wave 3 skips A j=2,3 (rows 112..127, read only by the skipped fr=3).
    const _Float16* ag[4];
    const _Float16* bg[4];
    _Float16* al[4];
    _Float16* bl[4];
#pragma unroll
    for (int j = 0; j < 4; ++j) {
        const int r = w * 32 + j * 8 + srow;
        ag[j] = Asp + ((size_t)b * T_ + r) * KS_ + sc16 * 8;
        bg[j] = Wsp + (size_t)(n0 + r) * KS_ + sc16 * 8;
        al[j] = &sm.g.A[(w * 32 + j * 8) * 64];
        bl[j] = &sm.g.Bm[(w * 32 + j * 8) * 64];
    }

    floatx4 acc[4][4];
#pragma unroll
    for (int i = 0; i < 4; ++i)
#pragma unroll
        for (int q = 0; q < 4; ++q) acc[i][q] = (floatx4){0.f, 0.f, 0.f, 0.f};

    const int quad = lane >> 4;
    const int l15 = lane & 15;
    const int l7 = lane & 7;

    for (int kt = 0; kt < 24; ++kt) {
        // segment map: kt 0..7 xh*wh, 8..15 xh*wl, 16..23 xl*wh
        const int koA = ((kt & 16) ? 512 : 0) + (kt & 7) * 64;
        const int koB = ((kt & 8)  ? 512 : 0) + (kt & 7) * 64;
        __syncthreads();
#pragma unroll
        for (int j = 0; j < 4; ++j) {
            if (j < 2 || w < 3) ld_g2l(ag[j] + koA, al[j]);
            ld_g2l(bg[j] + koB, bl[j]);
        }
        __syncthreads();
#pragma unroll
        for (int ks = 0; ks < 2; ++ks) {
            const int c16 = (ks * 4 + quad) ^ l7;   // physical (swizzled) k16
            half8 av[3], bv[4];
#pragma unroll
            for (int f = 0; f < 3; ++f)
                av[f] = *(const half8*)&sm.g.A[(wm + f * 16 + l15) * 64 + c16 * 8];
#pragma unroll
            for (int f = 0; f < 4; ++f)
                bv[f] = *(const half8*)&sm.g.Bm[(wn + f * 16 + l15) * 64 + c16 * 8];
#pragma unroll
            for (int fr = 0; fr < 3; ++fr)
#pragma unroll
                for (int fn = 0; fn < 4; ++fn)
                    acc[fr][fn] = __builtin_amdgcn_mfma_f32_16x16x32_f16(
                        av[fr], bv[fn], acc[fr][fn], 0, 0, 0);
            if (wm == 0) {   // fr=3 (tile rows 48..63) only valid for wm=0 waves
                half8 a3 = *(const half8*)&sm.g.A[(48 + l15) * 64 + c16 * 8];
#pragma unroll
                for (int fn = 0; fn < 4; ++fn)
                    acc[3][fn] = __builtin_amdgcn_mfma_f32_16x16x32_f16(
                        a3, bv[fn], acc[3][fn], 0, 0, 0);
            }
        }
    }

    // ---- epilogue: acc -> LDS (two 64-row phases) -> serial LIF scan ----
    float b1c[4];
#pragma unroll
    for (int fn = 0; fn < 4; ++fn) b1c[fn] = b1[n0 + wn + fn * 16 + l15];

    float mem = 0.f, ss = 0.f;
    const int myh = tid & 127;     // scan column for threads 0..127

    __syncthreads();               // all k-loop ds_reads done before overwrite
    // phase A: waves 0,1 (wm=0) hold C rows 0..63 = t 0..63 (fr 0..3)
    if (w < 2) {
#pragma unroll
        for (int fr = 0; fr < 4; ++fr)
#pragma unroll
            for (int r = 0; r < 4; ++r) {
                float* dst = &sm.Cs[(fr * 16 + quad * 4 + r) * CP + wn + l15];
#pragma unroll
                for (int fn = 0; fn < 4; ++fn)
                    dst[fn * 16] = acc[fr][fn][r] * ISC + b1c[fn];
            }
    }
    __syncthreads();
    if (tid < 128) {
#pragma unroll 8
        for (int t = 0; t < 64; ++t) {
            float c = sm.Cs[t * CP + myh];
            float reset = (mem > 1.0f) ? 1.0f : 0.0f;
            mem = 0.9f * mem + c - reset;
            ss += (mem > 1.0f) ? 1.0f : 0.0f;
        }
    }
    __syncthreads();
    // phase B: waves 2,3 hold C rows 64..111 (fr 0..2); scan needs 64..99
    if (w >= 2) {
#pragma unroll
        for (int fr = 0; fr < 3; ++fr)
#pragma unroll
            for (int r = 0; r < 4; ++r) {
                float* dst = &sm.Cs[(fr * 16 + quad * 4 + r) * CP + wn + l15];
#pragma unroll
                for (int fn = 0; fn < 4; ++fn)
                    dst[fn * 16] = acc[fr][fn][r] * ISC + b1c[fn];
            }
    }
    __syncthreads();
    if (tid < 128) {
#pragma unroll 6
        for (int t = 0; t < 36; ++t) {   // t global 64..99
            float c = sm.Cs[t * CP + myh];
            float reset = (mem > 1.0f) ? 1.0f : 0.0f;
            mem = 0.9f * mem + c - reset;
            ss += (mem > 1.0f) ? 1.0f : 0.0f;
        }
        // ---- FC2: logits[b][c] += sum_h ss * W2[c][h] ----
#pragma unroll
        for (int c = 0; c < C_; ++c) {
            float v = ss * W2[c * H_ + n0 + myh];
#pragma unroll
            for (int off = 32; off; off >>= 1) v += __shfl_down(v, off, 64);
            if (lane == 0) atomicAdd(&logits[b * C_ + c], v);
        }
    }
}

extern "C" void kernel_launch(void* const* d_in, const int* in_sizes, int n_in,
                              void* d_out, int out_size, void* d_ws, size_t ws_size,
                              hipStream_t stream) {
    const float* x  = (const float*)d_in[0];
    const float* W1 = (const float*)d_in[1];
    const float* b1 = (const float*)d_in[2];
    const float* W2 = (const float*)d_in[3];
    const float* b2 = (const float*)d_in[4];
    float* out = (float*)d_out;

    // workspace: Asp [25600][1024] f16, Wsp [1024][1024] f16 directly after
    // (fused kernel's tail rows overread into Wsp by design).
    char* ws = (char*)d_ws;
    _Float16* Asp = (_Float16*)ws;
    _Float16* Wsp = (_Float16*)(ws + (size_t)M_ * KS_ * 2);

    hipLaunchKernelGGL(split_all, dim3((M_ + H_) * 64 / 256), dim3(256), 0, stream,
                       x, W1, b2, Asp, out);
    hipLaunchKernelGGL(snn_mfma, dim3(B_ * 8), dim3(256), 0, stream,
                       Asp, Wsp, b1, W2, out);
}